// Round 3
// baseline (198.799 us; speedup 1.0000x reference)
//
#include <hip/hip_runtime.h>
#include <stdint.h>

#define B_ 4
#define T_ 4096
#define D_ 512
#define H_ 8
#define HD_ 64
#define W_ 5
#define M_ (B_*T_)     // 16384 rows
#define TM 160         // 128 q rows + 16 halo each side (supports dil<=4)
#define TN 192         // qh|kh|vh (64 each)
#define HALO 16
#define LSTR 72        // LDS tile row stride (elements); breaks epilogue bank conflicts

typedef __attribute__((ext_vector_type(8))) short short8;
typedef __attribute__((ext_vector_type(4))) float floatx4;

__device__ __forceinline__ unsigned short f2bf(float f) {
    unsigned int u = __builtin_bit_cast(unsigned int, f);
    u += 0x7fffu + ((u >> 16) & 1u);          // RNE
    return (unsigned short)(u >> 16);
}
__device__ __forceinline__ float bf2f(unsigned short s) {
    unsigned int u = ((unsigned int)s) << 16;
    return __builtin_bit_cast(float, u);
}
__device__ __forceinline__ void load8bf(const unsigned short* p, float* f) {
    uint4 d = *(const uint4*)p;
    f[0] = bf2f((unsigned short)(d.x & 0xffffu));
    f[1] = bf2f((unsigned short)(d.x >> 16));
    f[2] = bf2f((unsigned short)(d.y & 0xffffu));
    f[3] = bf2f((unsigned short)(d.y >> 16));
    f[4] = bf2f((unsigned short)(d.z & 0xffffu));
    f[5] = bf2f((unsigned short)(d.z >> 16));
    f[6] = bf2f((unsigned short)(d.w & 0xffffu));
    f[7] = bf2f((unsigned short)(d.w >> 16));
}

// async global->LDS, 16B/lane; LDS dest = wave-uniform base + lane*16
__device__ __forceinline__ void async16(const unsigned short* g, unsigned short* l) {
    __builtin_amdgcn_global_load_lds(
        (const __attribute__((address_space(1))) unsigned int*)g,
        (__attribute__((address_space(3))) unsigned int*)l, 16, 0, 0);
}

// ---------------- convert X (fp32 -> bf16), 8 elems/thread ----------------
__global__ __launch_bounds__(256) void convert_x(const float* __restrict__ x,
                                                 unsigned short* __restrict__ xb) {
    int i = blockIdx.x * 256 + threadIdx.x;
    const float4* x4 = (const float4*)x;
    float4 a = x4[2*i], b = x4[2*i + 1];
    uint4 o;
    o.x = (unsigned)f2bf(a.x) | ((unsigned)f2bf(a.y) << 16);
    o.y = (unsigned)f2bf(a.z) | ((unsigned)f2bf(a.w) << 16);
    o.z = (unsigned)f2bf(b.x) | ((unsigned)f2bf(b.y) << 16);
    o.w = (unsigned)f2bf(b.z) | ((unsigned)f2bf(b.w) << 16);
    ((uint4*)xb)[i] = o;
}

// ------ build Wt2[h][n192][k]: per-head packed qh|kh|vh weight rows -------
__global__ __launch_bounds__(256) void convert_w2(const float* __restrict__ Wq,
                                                  const float* __restrict__ Wk,
                                                  const float* __restrict__ Wv,
                                                  unsigned short* __restrict__ Wt2) {
    int tid = blockIdx.x * 256 + threadIdx.x;    // 1536*64 threads
    int np = tid % 1536;                         // h*192 + n192
    int kc = tid / 1536;                         // k chunk of 8
    int h = np / 192, n192 = np % 192;
    int sel = n192 >> 6, ch = n192 & 63;
    int c = h * 64 + ch;
    const float* Wsrc = (sel == 0) ? Wq : ((sel == 1) ? Wk : Wv);
    unsigned short us[8];
#pragma unroll
    for (int j = 0; j < 8; j++)
        us[j] = f2bf(Wsrc[(size_t)(kc*8 + j) * D_ + c]);
    uint4 o;
    o.x = (unsigned)us[0] | ((unsigned)us[1] << 16);
    o.y = (unsigned)us[2] | ((unsigned)us[3] << 16);
    o.z = (unsigned)us[4] | ((unsigned)us[5] << 16);
    o.w = (unsigned)us[6] | ((unsigned)us[7] << 16);
    *(uint4*)(Wt2 + (size_t)np * D_ + kc*8) = o;
}

// -------- fused per-head QKV GEMM + windowed attention --------------------
// grid: 1024 blocks = (M_/128) tiles x 8 heads, tile-major (h inner) for L2.
// Phase 1: 160x192x512 bf16 MFMA GEMM (m97-style global_load_lds staging).
// Phase 2: +bias -> LDS q/k/v tiles (stride 72). Phase 3: windowed softmax
// + PV from LDS, write out/attn. No Cb intermediate in HBM.
__global__ __launch_bounds__(256) void fused_qkv_attn(
    const unsigned short* __restrict__ Xb,   // [M_,512] bf16
    const unsigned short* __restrict__ Wt2,  // [8,192,512] bf16
    const float* __restrict__ bq, const float* __restrict__ bk2,
    const float* __restrict__ bv, const float* __restrict__ Er,
    const int* __restrict__ layer_p,
    float* __restrict__ out,                 // [B_,T_,512] fp32
    float* __restrict__ attn_out)            // [B_,8,T_,5] fp32
{
    __shared__ unsigned short SH[3 * TM * LSTR];   // 69120 B union
    __shared__ float sEr[HD_ * W_];
    unsigned short* As = SH;                       // [160*32]  (GEMM phase)
    unsigned short* Bs = SH + TM * 32;             // [192*32]
    unsigned short* Qs = SH;                       // [160*72]  (attn phase)
    unsigned short* Ks = SH + TM * LSTR;
    unsigned short* Vs = SH + 2 * TM * LSTR;

    const int tid = threadIdx.x;
    const int wave = tid >> 6, lane = tid & 63;
    const int tile = blockIdx.x >> 3, h = blockIdx.x & 7;
    const int b = tile >> 5;                       // 32 tiles per batch
    const int t0 = (tile & 31) * 128;
    const long m0g = (long)b * T_ + t0;

    for (int i = tid; i < HD_ * W_; i += 256)
        sEr[i] = Er[h * HD_ * W_ + i];

    // staging: 22 wave-issues of 16 rows x 64B (A:10, B:12); wave w takes q=w+4j
    const unsigned short* gsrc[6];
    unsigned short* ldst[6];
#pragma unroll
    for (int j = 0; j < 6; j++) {
        int q = wave + j * 4;
        if (q < 22) {
            if (q < 10) {
                long grow = m0g - HALO + q*16 + (lane >> 2);
                grow = grow < 0 ? 0 : (grow >= M_ ? M_ - 1 : grow);
                gsrc[j] = Xb + grow * D_ + (lane & 3) * 8;
                ldst[j] = As + q * 512;
            } else {
                int q2 = q - 10;
                gsrc[j] = Wt2 + ((size_t)h*192 + q2*16 + (lane >> 2)) * D_ + (lane & 3) * 8;
                ldst[j] = Bs + q2 * 512;
            }
        }
    }

    const int wm = (wave >> 1) * 80, wn = (wave & 1) * 96;
    const int qd = lane >> 4, r16 = lane & 15;
    floatx4 acc[5][6] = {};

    for (int kc = 0; kc < D_; kc += 32) {
#pragma unroll
        for (int j = 0; j < 6; j++)
            if (wave + j * 4 < 22)
                async16(gsrc[j] + kc, ldst[j]);
        __syncthreads();
        short8 af[5], bf[6];
#pragma unroll
        for (int mi = 0; mi < 5; mi++)
            af[mi] = __builtin_bit_cast(short8,
                *(const uint4*)(As + (wm + mi*16 + r16)*32 + qd*8));
#pragma unroll
        for (int ni = 0; ni < 6; ni++)
            bf[ni] = __builtin_bit_cast(short8,
                *(const uint4*)(Bs + (wn + ni*16 + r16)*32 + qd*8));
#pragma unroll
        for (int mi = 0; mi < 5; mi++)
#pragma unroll
            for (int ni = 0; ni < 6; ni++)
                acc[mi][ni] = __builtin_amdgcn_mfma_f32_16x16x32_bf16(
                    af[mi], bf[ni], acc[mi][ni], 0, 0, 0);
        __syncthreads();                     // reads done before next overwrite
    }

    // ---- epilogue: +bias, write q/k/v LDS tiles (overlays As/Bs, post-barrier)
#pragma unroll
    for (int ni = 0; ni < 6; ni++) {
        int n192 = wn + ni * 16 + r16;
        int sel = n192 >> 6;                 // wave-uniform per frag (16 | 64)
        int ch = n192 & 63;
        float bias = (sel == 0) ? bq[h*64 + ch]
                   : (sel == 1) ? bk2[h*64 + ch] : bv[h*64 + ch];
        unsigned short* tb = (sel == 0) ? Qs : (sel == 1) ? Ks : Vs;
#pragma unroll
        for (int mi = 0; mi < 5; mi++)
#pragma unroll
            for (int r = 0; r < 4; r++) {
                int l = wm + mi*16 + qd*4 + r;
                tb[l * LSTR + ch] = f2bf(acc[mi][ni][r] + bias);
            }
    }
    __syncthreads();

    // ---- attention from LDS: 8 lanes per token, 4 passes of 32 tokens ----
    const int dil = 1 << layer_p[0];
    const int sh = (h < 4) ? 0 : (h == 4 ? -2 : (h == 5 ? -1 : (h == 6 ? 1 : 2)));
    const int c8 = tid & 7, g32 = tid >> 3;

#pragma unroll
    for (int p = 0; p < 4; p++) {
        int tl = g32 + p * 32;               // local token 0..127
        int t = t0 + tl;
        float qf[8]; load8bf(Qs + (tl + HALO) * LSTR + c8 * 8, qf);

        int pos[W_]; bool val[W_]; float s[W_];
#pragma unroll
        for (int w = 0; w < W_; w++) {
            pos[w] = t + (sh + w - 2) * dil;
            val[w] = (pos[w] >= 0) && (pos[w] < T_);
            float a = 0.f;
            if (val[w]) {
                float kf[8]; load8bf(Ks + (pos[w] - t0 + HALO) * LSTR + c8 * 8, kf);
#pragma unroll
                for (int j = 0; j < 8; j++) a = fmaf(qf[j], kf[j], a);
            }
#pragma unroll
            for (int j = 0; j < 8; j++)
                a = fmaf(qf[j], sEr[(c8*8 + j) * W_ + w], a);
            s[w] = a;
        }
#pragma unroll
        for (int off = 4; off > 0; off >>= 1)
#pragma unroll
            for (int w = 0; w < W_; w++)
                s[w] += __shfl_xor(s[w], off, 8);

        float logit[W_], mx = -1e30f;
#pragma unroll
        for (int w = 0; w < W_; w++) {
            logit[w] = val[w] ? s[w] * 0.125f : -1e30f;
            mx = fmaxf(mx, logit[w]);
        }
        float pw[W_], ssum = 0.f;
#pragma unroll
        for (int w = 0; w < W_; w++) {
            pw[w] = val[w] ? __expf(logit[w] - mx) : 0.f;
            ssum += pw[w];
        }
        const float inv = 1.f / ssum;
        float aw[W_];
#pragma unroll
        for (int w = 0; w < W_; w++) aw[w] = pw[w] * inv;

        if (c8 < W_)
            attn_out[((size_t)(b * H_ + h) * T_ + t) * W_ + c8] = aw[c8];

        float of[8] = {0,0,0,0,0,0,0,0};
#pragma unroll
        for (int w = 0; w < W_; w++) {
            if (val[w]) {
                float vf[8]; load8bf(Vs + (pos[w] - t0 + HALO) * LSTR + c8 * 8, vf);
#pragma unroll
                for (int j = 0; j < 8; j++) of[j] = fmaf(aw[w], vf[j], of[j]);
            }
        }
        float* orow = out + ((size_t)b * T_ + t) * D_ + h * HD_ + c8 * 8;
        *(float4*)(orow)     = make_float4(of[0], of[1], of[2], of[3]);
        *(float4*)(orow + 4) = make_float4(of[4], of[5], of[6], of[7]);
    }
}

extern "C" void kernel_launch(void* const* d_in, const int* in_sizes, int n_in,
                              void* d_out, int out_size, void* d_ws, size_t ws_size,
                              hipStream_t stream) {
    const float* x   = (const float*)d_in[0];
    const float* Wq  = (const float*)d_in[1];
    const float* bq  = (const float*)d_in[2];
    const float* Wk  = (const float*)d_in[3];
    const float* bk  = (const float*)d_in[4];
    const float* Wv  = (const float*)d_in[5];
    const float* bv  = (const float*)d_in[6];
    const float* Er  = (const float*)d_in[7];
    const int* layer = (const int*)d_in[8];

    char* ws = (char*)d_ws;
    unsigned short* Xb  = (unsigned short*)ws;                          // 16 MB
    unsigned short* Wt2 = (unsigned short*)(ws + (size_t)16*1024*1024); // 1.5 MB

    float* out  = (float*)d_out;
    float* attn = out + (size_t)B_ * T_ * D_;

    convert_x<<<(M_ * D_ / 8) / 256, 256, 0, stream>>>(x, Xb);
    convert_w2<<<(1536 * 64) / 256, 256, 0, stream>>>(Wq, Wk, Wv, Wt2);
    fused_qkv_attn<<<(M_ / 128) * 8, 256, 0, stream>>>(Xb, Wt2, bq, bk, bv,
                                                       Er, layer, out, attn);
}

// Round 4
// 170.052 us; speedup vs baseline: 1.1690x; 1.1690x over previous
//
#include <hip/hip_runtime.h>
#include <stdint.h>

#define B_ 4
#define T_ 4096
#define D_ 512
#define H_ 8
#define HD_ 64
#define W_ 5
#define M_ (B_*T_)     // 16384 rows
#define TILE 64        // tokens per block
#define HALO 8         // supports dil<=2; input layer==1 -> dil=2
#define TMg 80         // GEMM rows: TILE + 2*HALO
#define TN 192         // qh|kh|vh
#define LSTR 72        // attn LDS row stride (16B-aligned, breaks conflicts)

typedef __attribute__((ext_vector_type(8))) short short8;
typedef __attribute__((ext_vector_type(4))) float floatx4;

__device__ __forceinline__ unsigned short f2bf(float f) {
    unsigned int u = __builtin_bit_cast(unsigned int, f);
    u += 0x7fffu + ((u >> 16) & 1u);          // RNE
    return (unsigned short)(u >> 16);
}
__device__ __forceinline__ float bf2f(unsigned short s) {
    unsigned int u = ((unsigned int)s) << 16;
    return __builtin_bit_cast(float, u);
}
__device__ __forceinline__ void load8bf(const unsigned short* p, float* f) {
    uint4 d = *(const uint4*)p;
    f[0] = bf2f((unsigned short)(d.x & 0xffffu));
    f[1] = bf2f((unsigned short)(d.x >> 16));
    f[2] = bf2f((unsigned short)(d.y & 0xffffu));
    f[3] = bf2f((unsigned short)(d.y >> 16));
    f[4] = bf2f((unsigned short)(d.z & 0xffffu));
    f[5] = bf2f((unsigned short)(d.z >> 16));
    f[6] = bf2f((unsigned short)(d.w & 0xffffu));
    f[7] = bf2f((unsigned short)(d.w >> 16));
}

// async global->LDS, 16B/lane; LDS dest = wave-uniform base + lane*16
__device__ __forceinline__ void async16(const unsigned short* g, unsigned short* l) {
    __builtin_amdgcn_global_load_lds(
        (const __attribute__((address_space(1))) unsigned int*)g,
        (__attribute__((address_space(3))) unsigned int*)l, 16, 0, 0);
}

// ---------------- convert X (fp32 -> bf16), 8 elems/thread ----------------
__global__ __launch_bounds__(256) void convert_x(const float* __restrict__ x,
                                                 unsigned short* __restrict__ xb) {
    int i = blockIdx.x * 256 + threadIdx.x;
    const float4* x4 = (const float4*)x;
    float4 a = x4[2*i], b = x4[2*i + 1];
    uint4 o;
    o.x = (unsigned)f2bf(a.x) | ((unsigned)f2bf(a.y) << 16);
    o.y = (unsigned)f2bf(a.z) | ((unsigned)f2bf(a.w) << 16);
    o.z = (unsigned)f2bf(b.x) | ((unsigned)f2bf(b.y) << 16);
    o.w = (unsigned)f2bf(b.z) | ((unsigned)f2bf(b.w) << 16);
    ((uint4*)xb)[i] = o;
}

// ------ build Wt2[h][n192][k]: per-head packed qh|kh|vh weight rows -------
__global__ __launch_bounds__(256) void convert_w2(const float* __restrict__ Wq,
                                                  const float* __restrict__ Wk,
                                                  const float* __restrict__ Wv,
                                                  unsigned short* __restrict__ Wt2) {
    int tid = blockIdx.x * 256 + threadIdx.x;    // 1536*64 threads
    int np = tid % 1536;                         // h*192 + n192
    int kc = tid / 1536;                         // k chunk of 8
    int h = np / 192, n192 = np % 192;
    int sel = n192 >> 6, ch = n192 & 63;
    int c = h * 64 + ch;
    const float* Wsrc = (sel == 0) ? Wq : ((sel == 1) ? Wk : Wv);
    unsigned short us[8];
#pragma unroll
    for (int j = 0; j < 8; j++)
        us[j] = f2bf(Wsrc[(size_t)(kc*8 + j) * D_ + c]);
    uint4 o;
    o.x = (unsigned)us[0] | ((unsigned)us[1] << 16);
    o.y = (unsigned)us[2] | ((unsigned)us[3] << 16);
    o.z = (unsigned)us[4] | ((unsigned)us[5] << 16);
    o.w = (unsigned)us[6] | ((unsigned)us[7] << 16);
    *(uint4*)(Wt2 + (size_t)np * D_ + kc*8) = o;
}

// -------- fused per-head QKV GEMM + windowed attention, small-block -------
// grid: 2048 = 256 token-tiles x 8 heads (h = bx&7 -> head pinned per XCD,
// keeps that head's 196KB weight slab L2-resident).
// Phase 1: 80x192x512 bf16 MFMA GEMM, m97 staging, 4 waves of 80x48.
// Phase 2: +bias -> LDS q(64)/k(80)/v(80) tiles stride 72.
// Phase 3: windowed softmax + PV from LDS. LDS union 32.9KB -> 4 blocks/CU.
__global__ __launch_bounds__(256) void fused_qkv_attn(
    const unsigned short* __restrict__ Xb,   // [M_,512] bf16
    const unsigned short* __restrict__ Wt2,  // [8,192,512] bf16
    const float* __restrict__ bq, const float* __restrict__ bk2,
    const float* __restrict__ bv, const float* __restrict__ Er,
    const int* __restrict__ layer_p,
    float* __restrict__ out,                 // [B_,T_,512] fp32
    float* __restrict__ attn_out)            // [B_,8,T_,5] fp32
{
    __shared__ unsigned short SH[(TILE + 2*TMg) * LSTR];   // 16128 elems = 32256B
    __shared__ float sEr[HD_ * W_];
    unsigned short* As = SH;                 // [80][32]   GEMM phase
    unsigned short* Bs = SH + TMg * 32;      // [192][32]  (2560..8704)
    unsigned short* Qs = SH;                 // [64][72]   attn phase
    unsigned short* Ks = SH + TILE * LSTR;   // [80][72]
    unsigned short* Vs = SH + (TILE + TMg) * LSTR;

    const int tid = threadIdx.x;
    const int wave = tid >> 6, lane = tid & 63;
    const int tile = blockIdx.x >> 3, h = blockIdx.x & 7;
    const int b = tile >> 6;                 // 64 tiles per batch
    const int t0 = (tile & 63) * TILE;
    const long m0g = (long)b * T_ + t0;

    for (int i = tid; i < HD_ * W_; i += 256)
        sEr[i] = Er[h * HD_ * W_ + i];

    // 17 staging issues (A:5, B:12), each 16 rows x 64B; wave w takes q=w+4j
    const unsigned short* gsrc[5];
    unsigned short* ldst[5];
#pragma unroll
    for (int j = 0; j < 5; j++) {
        int q = wave + j * 4;
        if (q < 17) {
            if (q < 5) {
                long grow = m0g - HALO + q*16 + (lane >> 2);
                grow = grow < 0 ? 0 : (grow >= M_ ? M_ - 1 : grow);  // halo garbage never read (masked)
                gsrc[j] = Xb + grow * D_ + (lane & 3) * 8;
                ldst[j] = As + q * 512;
            } else {
                int q2 = q - 5;
                gsrc[j] = Wt2 + ((size_t)h*TN + q2*16 + (lane >> 2)) * D_ + (lane & 3) * 8;
                ldst[j] = Bs + q2 * 512;
            }
        }
    }

    const int wn = wave * 48;                // wave-tile 80 x 48
    const int qd = lane >> 4, r16 = lane & 15;
    floatx4 acc[5][3] = {};

    for (int kc = 0; kc < D_; kc += 32) {
#pragma unroll
        for (int j = 0; j < 5; j++)
            if (wave + j * 4 < 17)
                async16(gsrc[j] + kc, ldst[j]);
        __syncthreads();
        short8 af[5], bf[3];
#pragma unroll
        for (int mi = 0; mi < 5; mi++)
            af[mi] = __builtin_bit_cast(short8,
                *(const uint4*)(As + (mi*16 + r16)*32 + qd*8));
#pragma unroll
        for (int ni = 0; ni < 3; ni++)
            bf[ni] = __builtin_bit_cast(short8,
                *(const uint4*)(Bs + (wn + ni*16 + r16)*32 + qd*8));
#pragma unroll
        for (int mi = 0; mi < 5; mi++)
#pragma unroll
            for (int ni = 0; ni < 3; ni++)
                acc[mi][ni] = __builtin_amdgcn_mfma_f32_16x16x32_bf16(
                    af[mi], bf[ni], acc[mi][ni], 0, 0, 0);
        __syncthreads();
    }

    // ---- epilogue: +bias, scatter to Q/K/V LDS tiles (overlays As/Bs) ----
#pragma unroll
    for (int ni = 0; ni < 3; ni++) {
        int n192 = wn + ni * 16 + r16;
        int sel = n192 >> 6;                 // uniform per (wave, ni)
        int ch = n192 & 63;
        float bias = (sel == 0) ? bq[h*64 + ch]
                   : (sel == 1) ? bk2[h*64 + ch] : bv[h*64 + ch];
#pragma unroll
        for (int mi = 0; mi < 5; mi++)
#pragma unroll
            for (int r = 0; r < 4; r++) {
                int l = mi*16 + qd*4 + r;    // 0..79
                unsigned short vb = f2bf(acc[mi][ni][r] + bias);
                if (sel == 0) {
                    if (l >= HALO && l < HALO + TILE)
                        Qs[(l - HALO) * LSTR + ch] = vb;
                } else if (sel == 1) {
                    Ks[l * LSTR + ch] = vb;
                } else {
                    Vs[l * LSTR + ch] = vb;
                }
            }
    }
    __syncthreads();

    // ---- attention from LDS: 8 lanes/token, 2 passes of 32 tokens --------
    const int dil = 1 << layer_p[0];
    const int sh = (h < 4) ? 0 : (h == 4 ? -2 : (h == 5 ? -1 : (h == 6 ? 1 : 2)));
    const int c8 = tid & 7, g32 = tid >> 3;

#pragma unroll
    for (int p = 0; p < 2; p++) {
        int tl = g32 + p * 32;               // local token 0..63
        int t = t0 + tl;
        float qf[8]; load8bf(Qs + tl * LSTR + c8 * 8, qf);

        int pos[W_]; bool val[W_]; float s[W_];
#pragma unroll
        for (int w = 0; w < W_; w++) {
            pos[w] = t + (sh + w - 2) * dil;
            val[w] = (pos[w] >= 0) && (pos[w] < T_);
            float a = 0.f;
            if (val[w]) {
                float kf[8]; load8bf(Ks + (pos[w] - t0 + HALO) * LSTR + c8 * 8, kf);
#pragma unroll
                for (int j = 0; j < 8; j++) a = fmaf(qf[j], kf[j], a);
            }
#pragma unroll
            for (int j = 0; j < 8; j++)
                a = fmaf(qf[j], sEr[(c8*8 + j) * W_ + w], a);
            s[w] = a;
        }
#pragma unroll
        for (int off = 4; off > 0; off >>= 1)
#pragma unroll
            for (int w = 0; w < W_; w++)
                s[w] += __shfl_xor(s[w], off, 8);

        float logit[W_], mx = -1e30f;
#pragma unroll
        for (int w = 0; w < W_; w++) {
            logit[w] = val[w] ? s[w] * 0.125f : -1e30f;
            mx = fmaxf(mx, logit[w]);
        }
        float pw[W_], ssum = 0.f;
#pragma unroll
        for (int w = 0; w < W_; w++) {
            pw[w] = val[w] ? __expf(logit[w] - mx) : 0.f;
            ssum += pw[w];
        }
        const float inv = 1.f / ssum;
        float aw[W_];
#pragma unroll
        for (int w = 0; w < W_; w++) aw[w] = pw[w] * inv;

        if (c8 < W_)
            attn_out[((size_t)(b * H_ + h) * T_ + t) * W_ + c8] = aw[c8];

        float of[8] = {0,0,0,0,0,0,0,0};
#pragma unroll
        for (int w = 0; w < W_; w++) {
            if (val[w]) {
                float vf[8]; load8bf(Vs + (pos[w] - t0 + HALO) * LSTR + c8 * 8, vf);
#pragma unroll
                for (int j = 0; j < 8; j++) of[j] = fmaf(aw[w], vf[j], of[j]);
            }
        }
        float* orow = out + ((size_t)b * T_ + t) * D_ + h * HD_ + c8 * 8;
        *(float4*)(orow)     = make_float4(of[0], of[1], of[2], of[3]);
        *(float4*)(orow + 4) = make_float4(of[4], of[5], of[6], of[7]);
    }
}

extern "C" void kernel_launch(void* const* d_in, const int* in_sizes, int n_in,
                              void* d_out, int out_size, void* d_ws, size_t ws_size,
                              hipStream_t stream) {
    const float* x   = (const float*)d_in[0];
    const float* Wq  = (const float*)d_in[1];
    const float* bq  = (const float*)d_in[2];
    const float* Wk  = (const float*)d_in[3];
    const float* bk  = (const float*)d_in[4];
    const float* Wv  = (const float*)d_in[5];
    const float* bv  = (const float*)d_in[6];
    const float* Er  = (const float*)d_in[7];
    const int* layer = (const int*)d_in[8];

    char* ws = (char*)d_ws;
    unsigned short* Xb  = (unsigned short*)ws;                          // 16 MB
    unsigned short* Wt2 = (unsigned short*)(ws + (size_t)16*1024*1024); // 1.5 MB

    float* out  = (float*)d_out;
    float* attn = out + (size_t)B_ * T_ * D_;

    convert_x<<<(M_ * D_ / 8) / 256, 256, 0, stream>>>(x, Xb);
    convert_w2<<<(1536 * 64) / 256, 256, 0, stream>>>(Wq, Wk, Wv, Wt2);
    fused_qkv_attn<<<(M_ / TILE) * 8, 256, 0, stream>>>(Xb, Wt2, bq, bk, bv,
                                                        Er, layer, out, attn);
}

// Round 5
// 157.539 us; speedup vs baseline: 1.2619x; 1.0794x over previous
//
#include <hip/hip_runtime.h>
#include <stdint.h>

#define B_ 4
#define T_ 4096
#define D_ 512
#define H_ 8
#define HD_ 64
#define W_ 5
#define M_ (B_*T_)     // 16384 rows
#define TILE 64        // tokens per block
#define HALO 8         // supports dil<=2; input layer==1 -> dil=2
#define TMg 80         // GEMM rows: TILE + 2*HALO
#define TN 192         // qh|kh|vh
#define LSTR 72        // attn LDS row stride (16B-aligned, breaks conflicts)

// LDS layout (shorts): As0[2560] As1[2560] Bs0[6144] Bs1[6144] = 17408
#define AS1_OFF 2560
#define BS0_OFF 5120
#define BS1_OFF 11264
#define SH_ELEMS 17408

typedef __attribute__((ext_vector_type(8))) short short8;
typedef __attribute__((ext_vector_type(4))) float floatx4;

__device__ __forceinline__ unsigned short f2bf(float f) {
    unsigned int u = __builtin_bit_cast(unsigned int, f);
    u += 0x7fffu + ((u >> 16) & 1u);          // RNE
    return (unsigned short)(u >> 16);
}
__device__ __forceinline__ float bf2f(unsigned short s) {
    unsigned int u = ((unsigned int)s) << 16;
    return __builtin_bit_cast(float, u);
}
__device__ __forceinline__ void load8bf(const unsigned short* p, float* f) {
    uint4 d = *(const uint4*)p;
    f[0] = bf2f((unsigned short)(d.x & 0xffffu));
    f[1] = bf2f((unsigned short)(d.x >> 16));
    f[2] = bf2f((unsigned short)(d.y & 0xffffu));
    f[3] = bf2f((unsigned short)(d.y >> 16));
    f[4] = bf2f((unsigned short)(d.z & 0xffffu));
    f[5] = bf2f((unsigned short)(d.z >> 16));
    f[6] = bf2f((unsigned short)(d.w & 0xffffu));
    f[7] = bf2f((unsigned short)(d.w >> 16));
}

// async global->LDS, 16B/lane; LDS dest = wave-uniform base + lane*16
__device__ __forceinline__ void async16(const unsigned short* g, unsigned short* l) {
    __builtin_amdgcn_global_load_lds(
        (const __attribute__((address_space(1))) unsigned int*)g,
        (__attribute__((address_space(3))) unsigned int*)l, 16, 0, 0);
}

// ------------- prep: convert X (fp32->bf16) + build Wt2 ------------------
// blocks [0,4096): X convert, 8 elems/thread.
// blocks [4096,4480): Wt2[h][n192][k] = W_{q|k|v}[k][h*64+ch] per-head pack.
__global__ __launch_bounds__(256) void prep(const float* __restrict__ x,
                                            const float* __restrict__ Wq,
                                            const float* __restrict__ Wk,
                                            const float* __restrict__ Wv,
                                            unsigned short* __restrict__ xb,
                                            unsigned short* __restrict__ Wt2) {
    int bx = blockIdx.x;
    if (bx < 4096) {
        int i = bx * 256 + threadIdx.x;
        const float4* x4 = (const float4*)x;
        float4 a = x4[2*i], b = x4[2*i + 1];
        uint4 o;
        o.x = (unsigned)f2bf(a.x) | ((unsigned)f2bf(a.y) << 16);
        o.y = (unsigned)f2bf(a.z) | ((unsigned)f2bf(a.w) << 16);
        o.z = (unsigned)f2bf(b.x) | ((unsigned)f2bf(b.y) << 16);
        o.w = (unsigned)f2bf(b.z) | ((unsigned)f2bf(b.w) << 16);
        ((uint4*)xb)[i] = o;
    } else {
        int tid = (bx - 4096) * 256 + threadIdx.x;   // 1536*64 threads
        int np = tid % 1536;                         // h*192 + n192
        int kc = tid / 1536;                         // k chunk of 8
        int h = np / 192, n192 = np % 192;
        int sel = n192 >> 6, ch = n192 & 63;
        int c = h * 64 + ch;
        const float* Wsrc = (sel == 0) ? Wq : ((sel == 1) ? Wk : Wv);
        unsigned short us[8];
#pragma unroll
        for (int j = 0; j < 8; j++)
            us[j] = f2bf(Wsrc[(size_t)(kc*8 + j) * D_ + c]);
        uint4 o;
        o.x = (unsigned)us[0] | ((unsigned)us[1] << 16);
        o.y = (unsigned)us[2] | ((unsigned)us[3] << 16);
        o.z = (unsigned)us[4] | ((unsigned)us[5] << 16);
        o.w = (unsigned)us[6] | ((unsigned)us[7] << 16);
        *(uint4*)(Wt2 + (size_t)np * D_ + kc*8) = o;
    }
}

// -------- fused per-head QKV GEMM + windowed attention --------------------
// grid 2048 = 256 token-tiles x 8 heads (h = bx&7: head pinned per XCD ->
// that head's 196KB weight slab stays L2-resident).
// Phase 1: 80x192x512 bf16 GEMM, BK=64 as two 32-col half-buffers (keeps
// 64B LDS rows: conflict-free frag reads; global_load_lds dest contiguous).
// 8 K-iters -> half the vmcnt/barrier drains of BK=32.
// Phase 2: +bias -> LDS q/k/v tiles stride 72. Phase 3: windowed softmax+PV.
__global__ __launch_bounds__(256, 3) void fused_qkv_attn(
    const unsigned short* __restrict__ Xb,   // [M_,512] bf16
    const unsigned short* __restrict__ Wt2,  // [8,192,512] bf16
    const float* __restrict__ bq, const float* __restrict__ bk2,
    const float* __restrict__ bv, const float* __restrict__ Er,
    const int* __restrict__ layer_p,
    float* __restrict__ out,                 // [B_,T_,512] fp32
    float* __restrict__ attn_out)            // [B_,8,T_,5] fp32
{
    __shared__ unsigned short SH[SH_ELEMS];        // 34816 B union
    __shared__ float sEr[HD_ * W_];
    unsigned short* As0 = SH;                      // GEMM phase
    unsigned short* Bs0 = SH + BS0_OFF;
    unsigned short* Qs = SH;                       // attn phase overlay
    unsigned short* Ks = SH + TILE * LSTR;
    unsigned short* Vs = SH + (TILE + TMg) * LSTR;

    const int tid = threadIdx.x;
    const int wave = tid >> 6, lane = tid & 63;
    const int tile = blockIdx.x >> 3, h = blockIdx.x & 7;
    const int b = tile >> 6;                 // 64 tiles per batch
    const int t0 = (tile & 63) * TILE;
    const long m0g = (long)b * T_ + t0;

    for (int i = tid; i < HD_ * W_; i += 256)
        sEr[i] = Er[h * HD_ * W_ + i];

    // 17 staging issues per k-half (A:5, B:12), each 16 rows x 64B;
    // wave w takes q = w + 4j.  halfoff = LDS delta to the k-high buffer.
    const unsigned short* gsrc[5];
    unsigned short* ldst[5];
    int halfoff[5];
#pragma unroll
    for (int j = 0; j < 5; j++) {
        int q = wave + j * 4;
        if (q < 17) {
            if (q < 5) {
                long grow = m0g - HALO + q*16 + (lane >> 2);
                grow = grow < 0 ? 0 : (grow >= M_ ? M_ - 1 : grow);  // halo clamp; masked later
                gsrc[j] = Xb + grow * D_ + (lane & 3) * 8;
                ldst[j] = As0 + q * 512;
                halfoff[j] = AS1_OFF;
            } else {
                int q2 = q - 5;
                gsrc[j] = Wt2 + ((size_t)h*TN + q2*16 + (lane >> 2)) * D_ + (lane & 3) * 8;
                ldst[j] = Bs0 + q2 * 512;
                halfoff[j] = BS1_OFF - BS0_OFF;
            }
        }
    }

    const int wn = wave * 48;                // wave-tile 80 x 48
    const int qd = lane >> 4, r16 = lane & 15;
    floatx4 acc[5][3] = {};

    for (int kc = 0; kc < D_; kc += 64) {    // 8 iterations
#pragma unroll
        for (int j = 0; j < 5; j++)
            if (wave + j * 4 < 17) {
                async16(gsrc[j] + kc,      ldst[j]);
                async16(gsrc[j] + kc + 32, ldst[j] + halfoff[j]);
            }
        __syncthreads();
        short8 af[5][2], bf[3][2];
#pragma unroll
        for (int half = 0; half < 2; half++) {
            const unsigned short* Ab = SH + half * AS1_OFF;
            const unsigned short* Bb = SH + BS0_OFF + half * (BS1_OFF - BS0_OFF);
#pragma unroll
            for (int mi = 0; mi < 5; mi++)
                af[mi][half] = __builtin_bit_cast(short8,
                    *(const uint4*)(Ab + (mi*16 + r16)*32 + qd*8));
#pragma unroll
            for (int ni = 0; ni < 3; ni++)
                bf[ni][half] = __builtin_bit_cast(short8,
                    *(const uint4*)(Bb + (wn + ni*16 + r16)*32 + qd*8));
        }
#pragma unroll
        for (int half = 0; half < 2; half++)
#pragma unroll
            for (int mi = 0; mi < 5; mi++)
#pragma unroll
                for (int ni = 0; ni < 3; ni++)
                    acc[mi][ni] = __builtin_amdgcn_mfma_f32_16x16x32_bf16(
                        af[mi][half], bf[ni][half], acc[mi][ni], 0, 0, 0);
        __syncthreads();
    }

    // ---- epilogue: +bias, scatter to Q/K/V LDS tiles (overlays staging) --
#pragma unroll
    for (int ni = 0; ni < 3; ni++) {
        int n192 = wn + ni * 16 + r16;
        int sel = n192 >> 6;                 // uniform per (wave, ni)
        int ch = n192 & 63;
        float bias = (sel == 0) ? bq[h*64 + ch]
                   : (sel == 1) ? bk2[h*64 + ch] : bv[h*64 + ch];
#pragma unroll
        for (int mi = 0; mi < 5; mi++)
#pragma unroll
            for (int r = 0; r < 4; r++) {
                int l = mi*16 + qd*4 + r;    // 0..79
                unsigned short vb = f2bf(acc[mi][ni][r] + bias);
                if (sel == 0) {
                    if (l >= HALO && l < HALO + TILE)
                        Qs[(l - HALO) * LSTR + ch] = vb;
                } else if (sel == 1) {
                    Ks[l * LSTR + ch] = vb;
                } else {
                    Vs[l * LSTR + ch] = vb;
                }
            }
    }
    __syncthreads();

    // ---- attention from LDS: 8 lanes/token, 2 passes of 32 tokens --------
    const int dil = 1 << layer_p[0];
    const int sh = (h < 4) ? 0 : (h == 4 ? -2 : (h == 5 ? -1 : (h == 6 ? 1 : 2)));
    const int c8 = tid & 7, g32 = tid >> 3;

#pragma unroll
    for (int p = 0; p < 2; p++) {
        int tl = g32 + p * 32;               // local token 0..63
        int t = t0 + tl;
        float qf[8]; load8bf(Qs + tl * LSTR + c8 * 8, qf);

        int pos[W_]; bool val[W_]; float s[W_];
#pragma unroll
        for (int w = 0; w < W_; w++) {
            pos[w] = t + (sh + w - 2) * dil;
            val[w] = (pos[w] >= 0) && (pos[w] < T_);
            float a = 0.f;
            if (val[w]) {
                float kf[8]; load8bf(Ks + (pos[w] - t0 + HALO) * LSTR + c8 * 8, kf);
#pragma unroll
                for (int j = 0; j < 8; j++) a = fmaf(qf[j], kf[j], a);
            }
#pragma unroll
            for (int j = 0; j < 8; j++)
                a = fmaf(qf[j], sEr[(c8*8 + j) * W_ + w], a);
            s[w] = a;
        }
#pragma unroll
        for (int off = 4; off > 0; off >>= 1)
#pragma unroll
            for (int w = 0; w < W_; w++)
                s[w] += __shfl_xor(s[w], off, 8);

        float logit[W_], mx = -1e30f;
#pragma unroll
        for (int w = 0; w < W_; w++) {
            logit[w] = val[w] ? s[w] * 0.125f : -1e30f;
            mx = fmaxf(mx, logit[w]);
        }
        float pw[W_], ssum = 0.f;
#pragma unroll
        for (int w = 0; w < W_; w++) {
            pw[w] = val[w] ? __expf(logit[w] - mx) : 0.f;
            ssum += pw[w];
        }
        const float inv = 1.f / ssum;
        float aw[W_];
#pragma unroll
        for (int w = 0; w < W_; w++) aw[w] = pw[w] * inv;

        if (c8 < W_)
            attn_out[((size_t)(b * H_ + h) * T_ + t) * W_ + c8] = aw[c8];

        float of[8] = {0,0,0,0,0,0,0,0};
#pragma unroll
        for (int w = 0; w < W_; w++) {
            if (val[w]) {
                float vf[8]; load8bf(Vs + (pos[w] - t0 + HALO) * LSTR + c8 * 8, vf);
#pragma unroll
                for (int j = 0; j < 8; j++) of[j] = fmaf(aw[w], vf[j], of[j]);
            }
        }
        float* orow = out + ((size_t)b * T_ + t) * D_ + h * HD_ + c8 * 8;
        *(float4*)(orow)     = make_float4(of[0], of[1], of[2], of[3]);
        *(float4*)(orow + 4) = make_float4(of[4], of[5], of[6], of[7]);
    }
}

extern "C" void kernel_launch(void* const* d_in, const int* in_sizes, int n_in,
                              void* d_out, int out_size, void* d_ws, size_t ws_size,
                              hipStream_t stream) {
    const float* x   = (const float*)d_in[0];
    const float* Wq  = (const float*)d_in[1];
    const float* bq  = (const float*)d_in[2];
    const float* Wk  = (const float*)d_in[3];
    const float* bk  = (const float*)d_in[4];
    const float* Wv  = (const float*)d_in[5];
    const float* bv  = (const float*)d_in[6];
    const float* Er  = (const float*)d_in[7];
    const int* layer = (const int*)d_in[8];

    char* ws = (char*)d_ws;
    unsigned short* Xb  = (unsigned short*)ws;                          // 16 MB
    unsigned short* Wt2 = (unsigned short*)(ws + (size_t)16*1024*1024); // 1.5 MB

    float* out  = (float*)d_out;
    float* attn = out + (size_t)B_ * T_ * D_;

    prep<<<4096 + 384, 256, 0, stream>>>(x, Wq, Wk, Wv, Xb, Wt2);
    fused_qkv_attn<<<(M_ / TILE) * 8, 256, 0, stream>>>(Xb, Wt2, bq, bk, bv,
                                                        Er, layer, out, attn);
}

// Round 6
// 149.418 us; speedup vs baseline: 1.3305x; 1.0544x over previous
//
#include <hip/hip_runtime.h>
#include <stdint.h>

#define B_ 4
#define T_ 4096
#define D_ 512
#define H_ 8
#define HD_ 64
#define W_ 5
#define M_ (B_*T_)     // 16384 rows
#define TILE 128       // tokens per block
#define HALO 16        // >= dil*2 (layer==1 -> dil=2 needs 8); 16 rounds TMg to 160
#define TMg 160        // GEMM rows: TILE + 2*HALO
#define TN 192         // qh|kh|vh
#define LSTR 72        // attn LDS row stride (16B-aligned, breaks conflicts)

// GEMM-phase LDS layout (shorts): As0[160*32] As1[160*32] Bs0[192*32] Bs1[192*32]
#define AS1_OFF 5120
#define BS0_OFF 10240
#define BS1_OFF 16384
// attn overlay: Qs[128*72] Ks[160*72] Vs[160*72] = 32256 shorts (64512 B)
#define SH_ELEMS 32256

typedef __attribute__((ext_vector_type(8))) short short8;
typedef __attribute__((ext_vector_type(4))) float floatx4;

__device__ __forceinline__ unsigned short f2bf(float f) {
    unsigned int u = __builtin_bit_cast(unsigned int, f);
    u += 0x7fffu + ((u >> 16) & 1u);          // RNE
    return (unsigned short)(u >> 16);
}
__device__ __forceinline__ float bf2f(unsigned short s) {
    unsigned int u = ((unsigned int)s) << 16;
    return __builtin_bit_cast(float, u);
}
__device__ __forceinline__ void load8bf(const unsigned short* p, float* f) {
    uint4 d = *(const uint4*)p;
    f[0] = bf2f((unsigned short)(d.x & 0xffffu));
    f[1] = bf2f((unsigned short)(d.x >> 16));
    f[2] = bf2f((unsigned short)(d.y & 0xffffu));
    f[3] = bf2f((unsigned short)(d.y >> 16));
    f[4] = bf2f((unsigned short)(d.z & 0xffffu));
    f[5] = bf2f((unsigned short)(d.z >> 16));
    f[6] = bf2f((unsigned short)(d.w & 0xffffu));
    f[7] = bf2f((unsigned short)(d.w >> 16));
}

// async global->LDS, 16B/lane; LDS dest = wave-uniform base + lane*16
__device__ __forceinline__ void async16(const unsigned short* g, unsigned short* l) {
    __builtin_amdgcn_global_load_lds(
        (const __attribute__((address_space(1))) unsigned int*)g,
        (__attribute__((address_space(3))) unsigned int*)l, 16, 0, 0);
}

// ------------- prep: convert X (fp32->bf16) + build Wt2 ------------------
__global__ __launch_bounds__(256) void prep(const float* __restrict__ x,
                                            const float* __restrict__ Wq,
                                            const float* __restrict__ Wk,
                                            const float* __restrict__ Wv,
                                            unsigned short* __restrict__ xb,
                                            unsigned short* __restrict__ Wt2) {
    int bx = blockIdx.x;
    if (bx < 4096) {
        int i = bx * 256 + threadIdx.x;
        const float4* x4 = (const float4*)x;
        float4 a = x4[2*i], b = x4[2*i + 1];
        uint4 o;
        o.x = (unsigned)f2bf(a.x) | ((unsigned)f2bf(a.y) << 16);
        o.y = (unsigned)f2bf(a.z) | ((unsigned)f2bf(a.w) << 16);
        o.z = (unsigned)f2bf(b.x) | ((unsigned)f2bf(b.y) << 16);
        o.w = (unsigned)f2bf(b.z) | ((unsigned)f2bf(b.w) << 16);
        ((uint4*)xb)[i] = o;
    } else {
        int tid = (bx - 4096) * 256 + threadIdx.x;   // 1536*64 threads
        int np = tid % 1536;                         // h*192 + n192
        int kc = tid / 1536;                         // k chunk of 8
        int h = np / 192, n192 = np % 192;
        int sel = n192 >> 6, ch = n192 & 63;
        int c = h * 64 + ch;
        const float* Wsrc = (sel == 0) ? Wq : ((sel == 1) ? Wk : Wv);
        unsigned short us[8];
#pragma unroll
        for (int j = 0; j < 8; j++)
            us[j] = f2bf(Wsrc[(size_t)(kc*8 + j) * D_ + c]);
        uint4 o;
        o.x = (unsigned)us[0] | ((unsigned)us[1] << 16);
        o.y = (unsigned)us[2] | ((unsigned)us[3] << 16);
        o.z = (unsigned)us[4] | ((unsigned)us[5] << 16);
        o.w = (unsigned)us[6] | ((unsigned)us[7] << 16);
        *(uint4*)(Wt2 + (size_t)np * D_ + kc*8) = o;
    }
}

// -------- fused per-head QKV GEMM + windowed attention, 512-thread --------
// grid 1024 = 128 token-tiles x 8 heads (h = bx&7 pins head per XCD).
// Phase 1: 160x192x512 bf16 GEMM, BK=64 (two 32-col half-buffers keep 64B
// LDS rows for global_load_lds contiguity). 8 waves, wave-tile 80x48.
// Phase 2: +bias -> LDS q/k/v (stride 72). Phase 3: windowed softmax + PV.
// LDS 64.5KB -> 2 blocks/CU = 16 waves/CU.
__global__ __launch_bounds__(512, 4) void fused_qkv_attn(
    const unsigned short* __restrict__ Xb,   // [M_,512] bf16
    const unsigned short* __restrict__ Wt2,  // [8,192,512] bf16
    const float* __restrict__ bq, const float* __restrict__ bk2,
    const float* __restrict__ bv, const float* __restrict__ Er,
    const int* __restrict__ layer_p,
    float* __restrict__ out,                 // [B_,T_,512] fp32
    float* __restrict__ attn_out)            // [B_,8,T_,5] fp32
{
    __shared__ unsigned short SH[SH_ELEMS];        // 64512 B union
    __shared__ float sEr[HD_ * W_];
    unsigned short* As0 = SH;                      // GEMM phase
    unsigned short* Bs0 = SH + BS0_OFF;
    unsigned short* Qs = SH;                       // attn phase overlay
    unsigned short* Ks = SH + TILE * LSTR;
    unsigned short* Vs = SH + (TILE + TMg) * LSTR;

    const int tid = threadIdx.x;
    const int wave = tid >> 6, lane = tid & 63;
    const int tile = blockIdx.x >> 3, h = blockIdx.x & 7;
    const int b = tile >> 5;                 // 32 tiles per batch
    const int t0 = (tile & 31) * TILE;
    const long m0g = (long)b * T_ + t0;

    for (int i = tid; i < HD_ * W_; i += 512)
        sEr[i] = Er[h * HD_ * W_ + i];

    // 22 staging issues per k-half (A:10, B:12), each 16 rows x 64B;
    // wave w takes q = w + 8j (j<3).  halfoff = delta to k-high buffer.
    const unsigned short* gsrc[3];
    unsigned short* ldst[3];
    int halfoff[3];
#pragma unroll
    for (int j = 0; j < 3; j++) {
        int q = wave + j * 8;
        if (q < 22) {
            if (q < 10) {
                long grow = m0g - HALO + q*16 + (lane >> 2);
                grow = grow < 0 ? 0 : (grow >= M_ ? M_ - 1 : grow);  // halo clamp; masked later
                gsrc[j] = Xb + grow * D_ + (lane & 3) * 8;
                ldst[j] = As0 + q * 512;
                halfoff[j] = AS1_OFF;
            } else {
                int q2 = q - 10;
                gsrc[j] = Wt2 + ((size_t)h*TN + q2*16 + (lane >> 2)) * D_ + (lane & 3) * 8;
                ldst[j] = Bs0 + q2 * 512;
                halfoff[j] = BS1_OFF - BS0_OFF;
            }
        }
    }

    const int wm = (wave >> 2) * 80;         // 2 row-groups x 4 col-groups
    const int wn = (wave & 3) * 48;          // wave-tile 80 x 48
    const int qd = lane >> 4, r16 = lane & 15;
    floatx4 acc[5][3] = {};

    for (int kc = 0; kc < D_; kc += 64) {    // 8 iterations
#pragma unroll
        for (int j = 0; j < 3; j++)
            if (wave + j * 8 < 22) {
                async16(gsrc[j] + kc,      ldst[j]);
                async16(gsrc[j] + kc + 32, ldst[j] + halfoff[j]);
            }
        __syncthreads();
        short8 af[5][2], bf[3][2];
#pragma unroll
        for (int half = 0; half < 2; half++) {
            const unsigned short* Ab = SH + half * AS1_OFF;
            const unsigned short* Bb = SH + BS0_OFF + half * (BS1_OFF - BS0_OFF);
#pragma unroll
            for (int mi = 0; mi < 5; mi++)
                af[mi][half] = __builtin_bit_cast(short8,
                    *(const uint4*)(Ab + (wm + mi*16 + r16)*32 + qd*8));
#pragma unroll
            for (int ni = 0; ni < 3; ni++)
                bf[ni][half] = __builtin_bit_cast(short8,
                    *(const uint4*)(Bb + (wn + ni*16 + r16)*32 + qd*8));
        }
#pragma unroll
        for (int half = 0; half < 2; half++)
#pragma unroll
            for (int mi = 0; mi < 5; mi++)
#pragma unroll
                for (int ni = 0; ni < 3; ni++)
                    acc[mi][ni] = __builtin_amdgcn_mfma_f32_16x16x32_bf16(
                        af[mi][half], bf[ni][half], acc[mi][ni], 0, 0, 0);
        __syncthreads();
    }

    // ---- epilogue: +bias, scatter to Q/K/V LDS tiles (overlays staging) --
#pragma unroll
    for (int ni = 0; ni < 3; ni++) {
        int n192 = wn + ni * 16 + r16;
        int sel = n192 >> 6;                 // uniform per (wave, ni)
        int ch = n192 & 63;
        float bias = (sel == 0) ? bq[h*64 + ch]
                   : (sel == 1) ? bk2[h*64 + ch] : bv[h*64 + ch];
#pragma unroll
        for (int mi = 0; mi < 5; mi++)
#pragma unroll
            for (int r = 0; r < 4; r++) {
                int l = wm + mi*16 + qd*4 + r;    // 0..159
                unsigned short vb = f2bf(acc[mi][ni][r] + bias);
                if (sel == 0) {
                    if (l >= HALO && l < HALO + TILE)
                        Qs[(l - HALO) * LSTR + ch] = vb;
                } else if (sel == 1) {
                    Ks[l * LSTR + ch] = vb;
                } else {
                    Vs[l * LSTR + ch] = vb;
                }
            }
    }
    __syncthreads();

    // ---- attention from LDS: 8 lanes/token, 2 passes of 64 tokens --------
    const int dil = 1 << layer_p[0];
    const int sh = (h < 4) ? 0 : (h == 4 ? -2 : (h == 5 ? -1 : (h == 6 ? 1 : 2)));
    const int c8 = tid & 7, g64 = tid >> 3;  // 64 token-groups

#pragma unroll
    for (int p = 0; p < 2; p++) {
        int tl = g64 + p * 64;               // local token 0..127
        int t = t0 + tl;
        float qf[8]; load8bf(Qs + tl * LSTR + c8 * 8, qf);

        int pos[W_]; bool val[W_]; float s[W_];
#pragma unroll
        for (int w = 0; w < W_; w++) {
            pos[w] = t + (sh + w - 2) * dil;
            val[w] = (pos[w] >= 0) && (pos[w] < T_);
            float a = 0.f;
            if (val[w]) {
                float kf[8]; load8bf(Ks + (pos[w] - t0 + HALO) * LSTR + c8 * 8, kf);
#pragma unroll
                for (int j = 0; j < 8; j++) a = fmaf(qf[j], kf[j], a);
            }
#pragma unroll
            for (int j = 0; j < 8; j++)
                a = fmaf(qf[j], sEr[(c8*8 + j) * W_ + w], a);
            s[w] = a;
        }
#pragma unroll
        for (int off = 4; off > 0; off >>= 1)
#pragma unroll
            for (int w = 0; w < W_; w++)
                s[w] += __shfl_xor(s[w], off, 8);

        float logit[W_], mx = -1e30f;
#pragma unroll
        for (int w = 0; w < W_; w++) {
            logit[w] = val[w] ? s[w] * 0.125f : -1e30f;
            mx = fmaxf(mx, logit[w]);
        }
        float pw[W_], ssum = 0.f;
#pragma unroll
        for (int w = 0; w < W_; w++) {
            pw[w] = val[w] ? __expf(logit[w] - mx) : 0.f;
            ssum += pw[w];
        }
        const float inv = 1.f / ssum;
        float aw[W_];
#pragma unroll
        for (int w = 0; w < W_; w++) aw[w] = pw[w] * inv;

        if (c8 < W_)
            attn_out[((size_t)(b * H_ + h) * T_ + t) * W_ + c8] = aw[c8];

        float of[8] = {0,0,0,0,0,0,0,0};
#pragma unroll
        for (int w = 0; w < W_; w++) {
            if (val[w]) {
                float vf[8]; load8bf(Vs + (pos[w] - t0 + HALO) * LSTR + c8 * 8, vf);
#pragma unroll
                for (int j = 0; j < 8; j++) of[j] = fmaf(aw[w], vf[j], of[j]);
            }
        }
        float* orow = out + ((size_t)b * T_ + t) * D_ + h * HD_ + c8 * 8;
        *(float4*)(orow)     = make_float4(of[0], of[1], of[2], of[3]);
        *(float4*)(orow + 4) = make_float4(of[4], of[5], of[6], of[7]);
    }
}

extern "C" void kernel_launch(void* const* d_in, const int* in_sizes, int n_in,
                              void* d_out, int out_size, void* d_ws, size_t ws_size,
                              hipStream_t stream) {
    const float* x   = (const float*)d_in[0];
    const float* Wq  = (const float*)d_in[1];
    const float* bq  = (const float*)d_in[2];
    const float* Wk  = (const float*)d_in[3];
    const float* bk  = (const float*)d_in[4];
    const float* Wv  = (const float*)d_in[5];
    const float* bv  = (const float*)d_in[6];
    const float* Er  = (const float*)d_in[7];
    const int* layer = (const int*)d_in[8];

    char* ws = (char*)d_ws;
    unsigned short* Xb  = (unsigned short*)ws;                          // 16 MB
    unsigned short* Wt2 = (unsigned short*)(ws + (size_t)16*1024*1024); // 1.5 MB

    float* out  = (float*)d_out;
    float* attn = out + (size_t)B_ * T_ * D_;

    prep<<<4096 + 384, 256, 0, stream>>>(x, Wq, Wk, Wv, Xb, Wt2);
    fused_qkv_attn<<<(M_ / TILE) * 8, 512, 0, stream>>>(Xb, Wt2, bq, bk, bv,
                                                        Er, layer, out, attn);
}